// Round 3
// baseline (907.755 us; speedup 1.0000x reference)
//
#include <hip/hip_runtime.h>
#include <hip/hip_bf16.h>

#define N_USER 100000
#define N_PHOTO 200000
#define NEDGE 1000000
#define INF 256
#define OUTF 64

typedef unsigned short u16;
typedef __attribute__((ext_vector_type(8))) short short8;
typedef __attribute__((ext_vector_type(4))) float f32x4;

#define LDSPAD 264       // 256 + 8 pad: keeps 16B alignment, breaks pow2 bank stride

// f32 -> bf16 bits, round-to-nearest-even
__device__ inline u16 f2b(float f) {
    union { float f; unsigned u; } v; v.f = f;
    unsigned r = v.u + 0x7FFF + ((v.u >> 16) & 1);
    return (u16)(r >> 16);
}
__device__ inline float b2f(u16 h) {
    union { unsigned u; float f; } v; v.u = ((unsigned)h) << 16; return v.f;
}

// ---- dispatch 1: transpose both W -> bf16 Wt; zero deg arrays (1.2MB) and
// the f32 output accumulator (76.8MB). Grid-stride, int4/float4 stores.
__global__ __launch_bounds__(256) void prep0(const float* __restrict__ W_likes,
                                             const float* __restrict__ W_likedby,
                                             u16* __restrict__ Wt_likes,
                                             u16* __restrict__ Wt_likedby,
                                             int* __restrict__ deg_base,
                                             float* __restrict__ out) {
    const int tid = blockIdx.x * 256 + threadIdx.x;
    const int nt = gridDim.x * 256;
    const int OUT4 = (N_USER + N_PHOTO) * (OUTF / 4);   // 4,800,000 float4s
    float4 z4 = {0.f, 0.f, 0.f, 0.f};
    for (int i = tid; i < OUT4; i += nt) ((float4*)out)[i] = z4;
    int4 zi = {0, 0, 0, 0};
    for (int i = tid; i < 75000; i += nt) ((int4*)deg_base)[i] = zi;   // deg_photo+deg_user
    for (int i = tid; i < INF * OUTF; i += nt) {
        int n = i & (OUTF - 1), k = i >> 6;
        Wt_likes[n * INF + k]   = f2b(W_likes[i]);
        Wt_likedby[n * INF + k] = f2b(W_likedby[i]);
    }
}

// ---- dispatch 2: Wh = feats @ W + b for BOTH etypes; bf16 MFMA ----
__global__ __launch_bounds__(256) void proj_both(
    const float* __restrict__ user_feats, const float* __restrict__ photo_feats,
    const u16* __restrict__ Wt_likes, const u16* __restrict__ Wt_likedby,
    const float* __restrict__ b_likes, const float* __restrict__ b_likedby,
    u16* __restrict__ Wh_likes, u16* __restrict__ Wh_likedby)
{
    __shared__ u16 lds_wt[OUTF * LDSPAD];   // 33792 B -> 4 blocks/CU
    const int NB_USER_PROJ = (N_USER + 63) / 64;   // 1563
    int bb = blockIdx.x;
    const float* feats; const u16* Wt; const float* bias; u16* Wh; int nrows; int blk;
    if (bb < NB_USER_PROJ) { feats = user_feats;  Wt = Wt_likes;   bias = b_likes;   Wh = Wh_likes;   nrows = N_USER;  blk = bb; }
    else                   { feats = photo_feats; Wt = Wt_likedby; bias = b_likedby; Wh = Wh_likedby; nrows = N_PHOTO; blk = bb - NB_USER_PROJ; }

    int tid = threadIdx.x;
    for (int c = tid; c < (INF * OUTF) / 8; c += 256) {
        int n = c >> 5;
        int ko = (c & 31) * 8;
        *(short8*)&lds_wt[n * LDSPAD + ko] = *(const short8*)&Wt[n * INF + ko];
    }
    __syncthreads();

    int wave = tid >> 6, lane = tid & 63;
    int l15 = lane & 15, quad = lane >> 4;
    int r0 = blk * 64 + wave * 16;
    int arow = r0 + l15;
    bool arow_ok = arow < nrows;

    f32x4 acc[4] = {{0,0,0,0},{0,0,0,0},{0,0,0,0},{0,0,0,0}};
    const float4* ap = (const float4*)(feats + (size_t)(arow_ok ? arow : 0) * INF);

    #pragma unroll
    for (int ks = 0; ks < 8; ++ks) {
        float4 x = ap[ks * 8 + quad * 2 + 0];   // A[m=arow][k=ks*32+quad*8+j]
        float4 y = ap[ks * 8 + quad * 2 + 1];
        short8 a = { (short)f2b(x.x), (short)f2b(x.y), (short)f2b(x.z), (short)f2b(x.w),
                     (short)f2b(y.x), (short)f2b(y.y), (short)f2b(y.z), (short)f2b(y.w) };
        #pragma unroll
        for (int nt2 = 0; nt2 < 4; ++nt2) {
            short8 b = *(const short8*)&lds_wt[(nt2 * 16 + l15) * LDSPAD + ks * 32 + quad * 8];
            acc[nt2] = __builtin_amdgcn_mfma_f32_16x16x32_bf16(a, b, acc[nt2], 0, 0, 0);
        }
    }

    #pragma unroll
    for (int nt2 = 0; nt2 < 4; ++nt2) {
        int col = nt2 * 16 + l15;
        float bv = bias[col];
        #pragma unroll
        for (int r = 0; r < 4; ++r) {
            int row = r0 + quad * 4 + r;    // D: row=quad*4+reg, col=lane&15 (+16*nt)
            if (row < nrows) {
                Wh[(size_t)row * OUTF + col] = f2b(acc[nt2][r] + bv);
            }
        }
    }
}

// ---- dispatch 3: edge-parallel aggregation. One wave per edge: lane = feature.
// Lane loads Wh[src][lane] (coalesced 128B row, L3-resident) and atomicAdds into
// out[dst][lane] (coalesced 256B f32 atomic wave-op, no return -> no dep chain).
// 4 independent edges unrolled per iteration for MLP. Degree counted on lane 0.
__device__ inline void agg_etype(const u16* __restrict__ Wh,
                                 const int* __restrict__ src,
                                 const int* __restrict__ dst,
                                 int* __restrict__ deg,
                                 float* __restrict__ o,
                                 int lane, int gw, int nw)
{
    for (int e0 = gw * 4; e0 < NEDGE; e0 += nw * 4) {   // NEDGE % 4 == 0
        int s[4], d[4];
        #pragma unroll
        for (int k = 0; k < 4; ++k) { s[k] = src[e0 + k]; d[k] = dst[e0 + k]; }
        float v[4];
        #pragma unroll
        for (int k = 0; k < 4; ++k) v[k] = b2f(Wh[(size_t)s[k] * OUTF + lane]);
        if (lane == 0) {
            #pragma unroll
            for (int k = 0; k < 4; ++k) atomicAdd(&deg[d[k]], 1);
        }
        #pragma unroll
        for (int k = 0; k < 4; ++k) atomicAdd(&o[(size_t)d[k] * OUTF + lane], v[k]);
    }
}

__global__ __launch_bounds__(256) void agg_both(
    const u16* __restrict__ Wh_likes,
    const int* __restrict__ likes_src, const int* __restrict__ likes_dst,
    const u16* __restrict__ Wh_likedby,
    const int* __restrict__ likedby_src, const int* __restrict__ likedby_dst,
    int* __restrict__ deg_photo, int* __restrict__ deg_user,
    float* __restrict__ out)
{
    int lane = threadIdx.x & 63;
    int gw = blockIdx.x * 4 + (threadIdx.x >> 6);
    int nw = gridDim.x * 4;
    // likes: user -> photo (photo block of out); likedby: photo -> user (user block)
    agg_etype(Wh_likes, likes_src, likes_dst, deg_photo,
              out + (size_t)N_USER * OUTF, lane, gw, nw);
    agg_etype(Wh_likedby, likedby_src, likedby_dst, deg_user,
              out, lane, gw, nw);
}

// ---- dispatch 4: divide by degree (mean, 0-degree -> 0 stays 0) ----
__global__ __launch_bounds__(256) void normalize_out(const int* __restrict__ deg_user,
                                                     const int* __restrict__ deg_photo,
                                                     float* __restrict__ out) {
    const int TOT4 = (N_USER + N_PHOTO) * (OUTF / 4);   // 4,800,000
    int i = blockIdx.x * 256 + threadIdx.x;             // float4 index
    if (i >= TOT4) return;
    int node = i >> 4;                                  // 16 float4 per node
    int dg = (node < N_USER) ? deg_user[node] : deg_photo[node - N_USER];
    float inv = 1.0f / (float)(dg > 1 ? dg : 1);
    float4 v = ((const float4*)out)[i];
    v.x *= inv; v.y *= inv; v.z *= inv; v.w *= inv;
    ((float4*)out)[i] = v;
}

extern "C" void kernel_launch(void* const* d_in, const int* in_sizes, int n_in,
                              void* d_out, int out_size, void* d_ws, size_t ws_size,
                              hipStream_t stream) {
    const float* user_feats  = (const float*)d_in[0];
    const float* photo_feats = (const float*)d_in[1];
    const float* W_likes     = (const float*)d_in[2];
    const float* b_likes     = (const float*)d_in[3];
    const float* W_likedby   = (const float*)d_in[4];
    const float* b_likedby   = (const float*)d_in[5];
    const int* likes_src     = (const int*)d_in[6];
    const int* likes_dst     = (const int*)d_in[7];
    const int* likedby_src   = (const int*)d_in[8];
    const int* likedby_dst   = (const int*)d_in[9];

    char* ws = (char*)d_ws;
    // all offsets 16B-aligned; total ~39.7 MB
    u16* Wh_likes     = (u16*)(ws + 0);          // 12,800,000
    u16* Wh_likedby   = (u16*)(ws + 12800000);   // 25,600,000
    u16* Wt_likes     = (u16*)(ws + 38400000);   // 32,768
    u16* Wt_likedby   = (u16*)(ws + 38432768);   // 32,768
    int* deg_photo    = (int*)(ws + 38465536);   // 800,000 } contiguous: zeroed as one
    int* deg_user     = (int*)(ws + 39265536);   // 400,000 } 1.2MB int4 region in prep0

    float* out = (float*)d_out;

    prep0<<<2048, 256, 0, stream>>>(W_likes, W_likedby, Wt_likes, Wt_likedby,
                                    deg_photo, out);

    proj_both<<<(N_USER + 63) / 64 + (N_PHOTO + 63) / 64, 256, 0, stream>>>(
        user_feats, photo_feats, Wt_likes, Wt_likedby, b_likes, b_likedby,
        Wh_likes, Wh_likedby);

    agg_both<<<2048, 256, 0, stream>>>(
        Wh_likes, likes_src, likes_dst,
        Wh_likedby, likedby_src, likedby_dst,
        deg_photo, deg_user, out);

    normalize_out<<<((N_USER + N_PHOTO) * (OUTF / 4) + 255) / 256, 256, 0, stream>>>(
        deg_user, deg_photo, out);
}